// Round 1
// 311.764 us; speedup vs baseline: 1.0099x; 1.0099x over previous
//
#include <hip/hip_runtime.h>

#define NIMG    4991
#define RIRLEN  3968
#define NTHREADS 256
#define BPB      8           // blocks per batch element
#define INV_PI   0.31830988618379067f
#define SR_OVER_C 46.647230320699704f   // 16000 / 343

// ---- compile-time compact image-source table: all (x,y,z), |x|+|y|+|z| <= 15 ----
struct Tab { int v[NIMG]; };
static constexpr Tab make_tab() {
    Tab t{};
    int k = 0;
    for (int x = -15; x <= 15; ++x)
        for (int y = -15; y <= 15; ++y)
            for (int z = -15; z <= 15; ++z) {
                int ax = x < 0 ? -x : x;
                int ay = y < 0 ? -y : y;
                int az = z < 0 ? -z : z;
                if (ax + ay + az <= 15)
                    t.v[k++] = (x + 15) | ((y + 15) << 8) | ((z + 15) << 16);
            }
    return t;
}
__constant__ Tab c_tab = make_tab();

static __device__ __forceinline__ int iabs(int v) { return v < 0 ? -v : v; }

__global__ __launch_bounds__(NTHREADS)
void rir_kernel(const float* __restrict__ inp, float* __restrict__ out, int B) {
    const int b     = blockIdx.x / BPB;
    const int chunk = blockIdx.x % BPB;
    const int tid   = threadIdx.x;
    const int lane  = tid & 63;
    const int sub   = lane & 15;        // tap-lane within 16-lane image group
    const int grp   = (lane >> 4) & 3;  // image group 0..3 within wave
    const int wave  = tid >> 6;

    __shared__ float s_rir[RIRLEN];
    __shared__ float s_par[12];

    for (int t = tid; t < RIRLEN; t += NTHREADS) s_rir[t] = 0.0f;
    if (tid == 0) {
        const float* ip = inp + b * 12;
        float rx = ip[0], ry = ip[1], rz = ip[2];
        float mx = ip[3] * rx, my = ip[4] * ry, mz = ip[5] * rz;
        float sx = ip[6] * rx, sy = ip[7] * ry, sz = ip[8] * rz;
        float aw = __builtin_fmaf(ip[9],  0.84f, 0.01f);   // walls x,y (lo+hi both)
        float a4 = __builtin_fmaf(ip[10], 0.84f, 0.01f);   // floor  (z lo)
        float a5 = __builtin_fmaf(ip[11], 0.84f, 0.01f);   // ceil   (z hi)
        s_par[0] = rx; s_par[1] = ry; s_par[2] = rz;
        s_par[3] = mx; s_par[4] = my; s_par[5] = mz;
        s_par[6] = sx; s_par[7] = sy; s_par[8] = sz;
        // log2(tr) = 0.5 * log2(1 - a)   (v_log_f32 is log2)
        s_par[9]  = 0.5f * __builtin_amdgcn_logf(1.0f - aw);
        s_par[10] = 0.5f * __builtin_amdgcn_logf(1.0f - a4);
        s_par[11] = 0.5f * __builtin_amdgcn_logf(1.0f - a5);
        if (chunk == 0) {
            float dx = mx - sx, dy = my - sy, dz = mz - sz;
            out[(size_t)B * RIRLEN + b] = __builtin_fmaf(
                __builtin_sqrtf(dx * dx + dy * dy + dz * dz), SR_OVER_C, 40.0f);
        }
    }
    __syncthreads();

    // Per-lane Hann-table constants: this lane owns taps j = sub + 16k, k=0..4.
    // cos/sin(pi*(j-40)/40) -> (j-40)/80 revolutions for v_sin/v_cos.
    float cj[5], sj[5];
    #pragma unroll
    for (int k = 0; k < 5; ++k) {
        float rev = (float)(sub + 16 * k - 40) * (1.0f / 80.0f);
        cj[k] = __builtin_amdgcn_cosf(rev);
        sj[k] = __builtin_amdgcn_sinf(rev);
    }
    // sinc sign (-1)^j: j parity == lane parity for all k (stride 16). Fold 1/pi in.
    const float slane = (lane & 1) ? -INV_PI : INV_PI;

    const float rx = s_par[0], ry = s_par[1], rz = s_par[2];
    const float mx = s_par[3], my = s_par[4], mz = s_par[5];
    const float sx = s_par[6], sy = s_par[7], sz = s_par[8];
    const float lw = s_par[9], l4 = s_par[10], l5 = s_par[11];

    const int per = (NIMG + BPB - 1) / BPB;                 // 624
    const int i0  = chunk * per;
    const int i1  = (i0 + per < NIMG) ? (i0 + per) : NIMG;
    const int nr  = (per + 15) >> 4;                        // rounds: 16 images/round/wave-quad

    // round r, wave w, group g -> image i0 + r*16 + w*4 + g
    int idx = i0 + wave * 4 + grp;
    int p   = c_tab.v[idx < NIMG ? idx : NIMG - 1];

    for (int r = 0; r < nr; ++r) {
        const int idx_n = idx + 16;
        const int p_n   = c_tab.v[idx_n < NIMG ? idx_n : NIMG - 1];  // prefetch next round

        const int x = (p & 255) - 15;
        const int y = ((p >> 8) & 255) - 15;
        const int z = ((p >> 16) & 255) - 15;

        // image location per dim: odd -> room*(n+1) - src ; even -> room*n + src
        const float ix = (x & 1) ? __builtin_fmaf(rx, (float)(x + 1), -sx)
                                 : __builtin_fmaf(rx, (float)x, sx);
        const float iy = (y & 1) ? __builtin_fmaf(ry, (float)(y + 1), -sy)
                                 : __builtin_fmaf(ry, (float)y, sy);
        const float iz = (z & 1) ? __builtin_fmaf(rz, (float)(z + 1), -sz)
                                 : __builtin_fmaf(rz, (float)z, sz);

        const float dx = ix - mx, dy = iy - my, dz = iz - mz;
        const float dist  = __builtin_sqrtf(__builtin_fmaf(dx, dx, __builtin_fmaf(dy, dy, dz * dz)));
        const float delay = dist * SR_OVER_C;
        const float di    = __builtin_ceilf(delay);
        int ti0 = (int)di - 40;
        if (idx >= i1) ti0 = RIRLEN;      // invalid image -> every tap masked out

        // skip the round only if ALL four images are out of range (uniform branch)
        if (__ballot(ti0 < RIRLEN) != 0ull) {
            // att = prod tr^exp == exp2( sum e * log2(tr) )
            const int ew = iabs(x >> 1) + iabs((x + 1) >> 1) + iabs(y >> 1) + iabs((y + 1) >> 1);
            const float att = __builtin_amdgcn_exp2f(__builtin_fmaf((float)ew, lw,
                                  __builtin_fmaf((float)iabs(z >> 1), l4,
                                       (float)iabs((z + 1) >> 1) * l5)));
            const float amp  = att * __builtin_amdgcn_rcpf(dist);
            const float frac = di - delay;                 // in [0,1)
            // sin(pi*frac): pi*frac rad = frac/2 rev; sign + 1/pi folded via slane
            const float c1  = amp * __builtin_amdgcn_sinf(0.5f * frac) * slane;
            // hann angle pi*frac/40 rad = frac/80 rev
            const float ca  = 0.5f * __builtin_amdgcn_cosf(frac * (1.0f / 80.0f));
            const float nsa = -0.5f * __builtin_amdgcn_sinf(frac * (1.0f / 80.0f));

            const float x0 = frac + (float)(sub - 40);
            const int   t0 = ti0 + sub;
            #pragma unroll
            for (int k = 0; k < 5; ++k) {
                const float xv = x0 + (float)(16 * k);
                // hann(x) = 0.5 + ca*cos_j - sa*sin_j  (angle addition, per-lane table)
                const float h = __builtin_fmaf(ca, cj[k], __builtin_fmaf(nsa, sj[k], 0.5f));
                float v = c1 * h * __builtin_amdgcn_rcpf(xv);
                v = (xv == 0.0f) ? amp : v;                // sinc(0)*hann(0) = 1
                const int t = t0 + 16 * k;
                // 16 consecutive addresses per image group -> near-conflict-free ds_add
                if ((unsigned)t < (unsigned)RIRLEN) atomicAdd(&s_rir[t], v);
            }
        }
        idx = idx_n; p = p_n;
    }
    __syncthreads();

    float* orow = out + (size_t)b * RIRLEN;
    for (int t = tid; t < RIRLEN; t += NTHREADS) {
        const float v = s_rir[t];
        if (v != 0.0f) atomicAdd(&orow[t], v);
    }
}

extern "C" void kernel_launch(void* const* d_in, const int* in_sizes, int n_in,
                              void* d_out, int out_size, void* d_ws, size_t ws_size,
                              hipStream_t stream) {
    const float* inp = (const float*)d_in[0];
    float* out = (float*)d_out;
    const int B = in_sizes[0] / 12;
    (void)hipMemsetAsync(d_out, 0, (size_t)out_size * sizeof(float), stream);
    rir_kernel<<<dim3(B * BPB), dim3(NTHREADS), 0, stream>>>(inp, out, B);
}